// Round 8
// baseline (92.354 us; speedup 1.0000x reference)
//
#include <hip/hip_runtime.h>

#define NROWS 32768
#define NE    1024
#define ED    64
#define CHUNK 128              // codes per LDS chunk (32 KB transposed)
#define NCH   (NE / CHUNK)     // 8 chunks
#define RPW   8                // rows per wave
#define NW    8                // waves per block
#define RPB   (RPW * NW)       // 64 rows per block

typedef float4 f4;
typedef float2 f2;

// ---------------------------------------------------------------------------
// Prep: per-code ||e||^2 with numpy pairwise-8 op order (exact f32 replication)
// ---------------------------------------------------------------------------
__global__ void vq_prep(const float* __restrict__ cb, float* __restrict__ ssq)
{
    int j = blockIdx.x * blockDim.x + threadIdx.x;   // 0..1023
    const f4* crow = (const f4*)(cb + (size_t)j * ED);
    float v[ED];
#pragma unroll
    for (int i = 0; i < 16; ++i) {
        f4 t = crow[i];
        v[4*i+0] = t.x; v[4*i+1] = t.y; v[4*i+2] = t.z; v[4*i+3] = t.w;
    }
    {
#pragma clang fp contract(off)
        float r0 = v[0]*v[0], r1 = v[1]*v[1], r2 = v[2]*v[2], r3 = v[3]*v[3];
        float r4 = v[4]*v[4], r5 = v[5]*v[5], r6 = v[6]*v[6], r7 = v[7]*v[7];
#pragma unroll
        for (int i = 8; i < ED; i += 8) {
            r0 += v[i+0]*v[i+0]; r1 += v[i+1]*v[i+1];
            r2 += v[i+2]*v[i+2]; r3 += v[i+3]*v[i+3];
            r4 += v[i+4]*v[i+4]; r5 += v[i+5]*v[i+5];
            r6 += v[i+6]*v[i+6]; r7 += v[i+7]*v[i+7];
        }
        ssq[j] = ((r0+r1)+(r2+r3)) + ((r4+r5)+(r6+r7));
    }
}

// ---------------------------------------------------------------------------
// Main (r7 inner loop, 512-thread blocks for 8 waves/SIMD occupancy):
//  - block: 64 rows, 8 waves (8 rows each); waves independent.
//  - codebook chunk (128 codes) transposed in LDS [64 dim][128 code];
//    lane owns code pair {2*lane, 2*lane+1} (float2 reads, 2-way = free).
//  - z fragments (row, k4) wave-uniform -> s_load_dwordx4 (SMEM pipe);
//    inner loop: v_fmac v_acc, s_z, v_e. LDS pipe = e-reads only.
// Numerics identical per-row to passing rounds 3/6/7:
//   cn/ssq numpy pairwise-8; dot ascending-k single-acc fmaf;
//   d = fl(fl(cn+ssq_j) - 2*dot); first-index argmin (strict < ascending j,
//   lex (d,idx) across lanes).
// ---------------------------------------------------------------------------
__global__ __launch_bounds__(512, 8)
void vq_main(const float* __restrict__ z, const float* __restrict__ cb,
             const float* __restrict__ ssq, float* __restrict__ out,
             float* __restrict__ partials)
{
    __shared__ __align__(16) float et[ED * CHUNK];   // 32 KB transposed chunk
    __shared__ __align__(16) float sqsh[NE];         // 4 KB
    __shared__ int   idxsh[RPB];
    __shared__ float wsum[NW];

    const int tid  = threadIdx.x;
    const int lane = tid & 63;
    const int w    = tid >> 6;                               // wave 0..7
    const int w_u  = __builtin_amdgcn_readfirstlane(w);      // scalar wave id
    const int rowbase = blockIdx.x * RPB;

    // stage all 1024 ssq once (first chunk barrier fences it)
    if (tid < 256) ((f4*)sqsh)[tid] = ((const f4*)ssq)[tid];

    // ---- row norms for this wave's 8 rows, numpy pairwise-8 ----
    float cn[RPW];
    {
        const int rl = lane >> 3;            // row within wave's 8
        const int jj = lane & 7;             // accumulator index
        const float* zr = z + (size_t)(rowbase + w_u * RPW + rl) * ED;
        float a;
        {
#pragma clang fp contract(off)
            a = 0.f;
#pragma unroll
            for (int i = 0; i < 8; ++i) { float v = zr[8*i + jj]; a += v*v; }
        }
        a += __shfl_xor(a, 1);
        a += __shfl_xor(a, 2);
        a += __shfl_xor(a, 4);
#pragma unroll
        for (int r = 0; r < RPW; ++r) cn[r] = __shfl(a, r * 8);
    }

    float bestv[RPW];
    int   besti[RPW];
#pragma unroll
    for (int r = 0; r < RPW; ++r) { bestv[r] = INFINITY; besti[r] = 0; }

    const f2* et2 = (const f2*)et;                            // [64][64] f2
    const float* zw = z + (size_t)(rowbase + w_u * RPW) * ED; // scalar base

    for (int ch = 0; ch < NCH; ++ch) {
        __syncthreads();   // previous chunk's readers done (also fences sqsh)
        // ---- stage chunk transposed: 4 threads per code (16 dims each) ----
        {
            const int c = tid & 127;          // code within chunk
            const int h = tid >> 7;           // dim quarter 0..3
            const f4* crow = (const f4*)(cb + (size_t)(ch * CHUNK + c) * ED
                                         + h * 16);
#pragma unroll
            for (int i = 0; i < 4; ++i) {
                f4 t = crow[i];
                const int dim = h * 16 + 4 * i;
                et[(dim+0) * CHUNK + c] = t.x;
                et[(dim+1) * CHUNK + c] = t.y;
                et[(dim+2) * CHUNK + c] = t.z;
                et[(dim+3) * CHUNK + c] = t.w;
            }
        }
        __syncthreads();

        f2 sv = ((const f2*)sqsh)[ch * 64 + lane];
        float svq[2] = {sv.x, sv.y};

        float acc[RPW][2];
#pragma unroll
        for (int r = 0; r < RPW; ++r) acc[r][0] = acc[r][1] = 0.f;

#pragma unroll 2
        for (int k4 = 0; k4 < 16; ++k4) {
            // e: lane's code pair at dims 4k4..4k4+3 (LDS pipe, 2-way free)
            f2 e0 = et2[(4*k4+0) * 64 + lane];
            f2 e1 = et2[(4*k4+1) * 64 + lane];
            f2 e2 = et2[(4*k4+2) * 64 + lane];
            f2 e3 = et2[(4*k4+3) * 64 + lane];
            // z: wave-uniform fragments -> s_load_dwordx4 (SMEM pipe)
            f4 z0 = *(const f4*)(zw + 0*ED + 4*k4);
            f4 z1 = *(const f4*)(zw + 1*ED + 4*k4);
            f4 z2 = *(const f4*)(zw + 2*ED + 4*k4);
            f4 z3 = *(const f4*)(zw + 3*ED + 4*k4);
            f4 z4 = *(const f4*)(zw + 4*ED + 4*k4);
            f4 z5 = *(const f4*)(zw + 5*ED + 4*k4);
            f4 z6 = *(const f4*)(zw + 6*ED + 4*k4);
            f4 z7 = *(const f4*)(zw + 7*ED + 4*k4);
#define ROWFMA(r, zz)                                                    \
            acc[r][0] = fmaf(zz.x, e0.x, acc[r][0]);                     \
            acc[r][1] = fmaf(zz.x, e0.y, acc[r][1]);                     \
            acc[r][0] = fmaf(zz.y, e1.x, acc[r][0]);                     \
            acc[r][1] = fmaf(zz.y, e1.y, acc[r][1]);                     \
            acc[r][0] = fmaf(zz.z, e2.x, acc[r][0]);                     \
            acc[r][1] = fmaf(zz.z, e2.y, acc[r][1]);                     \
            acc[r][0] = fmaf(zz.w, e3.x, acc[r][0]);                     \
            acc[r][1] = fmaf(zz.w, e3.y, acc[r][1]);
            ROWFMA(0, z0) ROWFMA(1, z1) ROWFMA(2, z2) ROWFMA(3, z3)
            ROWFMA(4, z4) ROWFMA(5, z5) ROWFMA(6, z6) ROWFMA(7, z7)
#undef ROWFMA
        }

        {
#pragma clang fp contract(off)
#pragma unroll
            for (int r = 0; r < RPW; ++r) {
#pragma unroll
                for (int q = 0; q < 2; ++q) {
                    float t1 = cn[r] + svq[q];
                    float d  = t1 - 2.0f * acc[r][q];      // 2*acc exact
                    int j = ch * CHUNK + lane * 2 + q;
                    if (d < bestv[r]) { bestv[r] = d; besti[r] = j; }
                }
            }
        }
    }

    // ---- cross-lane lexicographic (val, idx) argmin + epilogue ----
    float lp = 0.f;
#pragma unroll
    for (int r = 0; r < RPW; ++r) {
        float v = bestv[r];
        int   i = besti[r];
#pragma unroll
        for (int m = 1; m < 64; m <<= 1) {
            float ov = __shfl_xor(v, m);
            int   oi = __shfl_xor(i, m);
            if (ov < v || (ov == v && oi < i)) { v = ov; i = oi; }
        }
        i &= (NE - 1);                       // defensive no-op
        const int grow = rowbase + w * RPW + r;
        float zq, zz, diff, st;
        {
#pragma clang fp contract(off)
            zq   = cb[(size_t)i * ED + lane];
            zz   = z [(size_t)grow * ED + lane];
            diff = zq - zz;                  // (z_q - z)
            st   = zz + diff;                // z + sg(z_q - z)
            lp  += diff * diff;
        }
        out[(size_t)grow * ED + lane] = st;
        if (lane == 0) idxsh[w * RPW + r] = i;
    }

    // ---- deterministic loss partial ----
#pragma unroll
    for (int m = 1; m < 64; m <<= 1) lp += __shfl_xor(lp, m);
    if (lane == 0) wsum[w] = lp;
    __syncthreads();

    // ---- uniform coalesced idx store (f32) ----
    if (tid < RPB) {
        int iv = idxsh[tid] & (NE - 1);
        out[(size_t)NROWS * ED + rowbase + tid] = (float)iv;
    }
    if (tid == 0)
        partials[blockIdx.x] = (((wsum[0]+wsum[1]) + (wsum[2]+wsum[3]))
                              + ((wsum[4]+wsum[5]) + (wsum[6]+wsum[7])));
}

// ---------------------------------------------------------------------------
// Finalize: deterministic tree-sum of 512 partials -> loss scalar (f32)
// ---------------------------------------------------------------------------
__global__ void vq_finalize(const float* __restrict__ partials,
                            float* __restrict__ out)
{
    __shared__ float red[256];
    int t = threadIdx.x;
    red[t] = partials[t] + partials[t + 256];
    __syncthreads();
    for (int m = 128; m > 0; m >>= 1) {
        if (t < m) red[t] += red[t + m];
        __syncthreads();
    }
    if (t == 0) {
        float mean = red[0] / (float)((size_t)NROWS * ED);
        out[(size_t)NROWS * ED + NROWS] = mean + 0.25f * mean;  // (1+BETA)*mean
    }
}

extern "C" void kernel_launch(void* const* d_in, const int* in_sizes, int n_in,
                              void* d_out, int out_size, void* d_ws, size_t ws_size,
                              hipStream_t stream)
{
    (void)in_sizes; (void)n_in; (void)out_size; (void)ws_size;
    const float* z  = (const float*)d_in[0];
    const float* cb = (const float*)d_in[1];
    float* out = (float*)d_out;
    float* ssq      = (float*)d_ws;          // 1024 f32
    float* partials = ssq + NE;              // 512 f32

    vq_prep<<<4, 256, 0, stream>>>(cb, ssq);
    vq_main<<<512, 512, 0, stream>>>(z, cb, ssq, out, partials);
    vq_finalize<<<1, 256, 0, stream>>>(partials, out);
}